// Round 1
// baseline (203.396 us; speedup 1.0000x reference)
//
#include <hip/hip_runtime.h>
#include <hip/hip_bf16.h>

// Problem constants
#define RTOT  65536      // B*K rows
#define DDIM  256
#define NCODE 512
#define LN_EPS 1e-5f

typedef short bf16x8 __attribute__((ext_vector_type(8)));
typedef float f32x4  __attribute__((ext_vector_type(4)));

__device__ __forceinline__ unsigned short f2bf(float f) {
  unsigned u = __float_as_uint(f);
  u += 0x7fffu + ((u >> 16) & 1u);          // RNE
  return (unsigned short)(u >> 16);
}
__device__ __forceinline__ float bf2f(unsigned short s) {
  return __uint_as_float(((unsigned)s) << 16);
}

// ---------------------------------------------------------------------------
// Prep kernel: bf16 casts of W_in/codebook, |c|^2, code_out = CB @ W_out^T,
// zero the loss accumulator.
// blocks [0,256): W_in->bf16 ; [256,768): codebook->bf16 + c2 ; [768,1280): code_out
// ---------------------------------------------------------------------------
__global__ __launch_bounds__(256) void prep_kernel(
    const float* __restrict__ codebook, const float* __restrict__ W_in,
    const float* __restrict__ W_out,
    float* __restrict__ loss_acc, float* __restrict__ c2,
    float* __restrict__ code_out, unsigned short* __restrict__ Wb,
    unsigned short* __restrict__ CBb) {
  __shared__ float ws4[4];
  __shared__ float cbl[256];
  const int b = blockIdx.x, t = threadIdx.x;
  if (b < 256) {
    int i = b * 256 + t;
    Wb[i] = f2bf(W_in[i]);
  } else if (b < 768) {
    int c = b - 256;
    float v = codebook[c * 256 + t];
    CBb[c * 256 + t] = f2bf(v);
    float sq = v * v;
    #pragma unroll
    for (int m = 1; m < 64; m <<= 1) sq += __shfl_xor(sq, m);
    if ((t & 63) == 0) ws4[t >> 6] = sq;
    __syncthreads();
    if (t == 0) {
      c2[c] = ws4[0] + ws4[1] + ws4[2] + ws4[3];
      if (c == 0) *loss_acc = 0.f;
    }
  } else {
    int c = b - 768;
    cbl[t] = codebook[c * 256 + t];
    __syncthreads();
    const float* wrow = W_out + t * 256;   // code_out[c][e] = sum_d cb[c,d]*W_out[e,d]
    float acc = 0.f;
    #pragma unroll 4
    for (int d = 0; d < 256; d += 4) {
      float4 w = *(const float4*)(wrow + d);
      acc += cbl[d] * w.x + cbl[d+1] * w.y + cbl[d+2] * w.z + cbl[d+3] * w.w;
    }
    code_out[c * 256 + t] = acc;
  }
}

// ---------------------------------------------------------------------------
// Main fused kernel: 64 rows per block, 256 threads (4 waves).
// Phase 1: Z = H * W_in^T (bf16 MFMA)  -> LDS (bf16)
// Phase 2: scores = Z * CB^T, argmin over 512 codes, dist -> atomic loss
// Phase 3: h = hidden + mask*code_out[idx]; LayerNorm; store
// ---------------------------------------------------------------------------
__global__ __launch_bounds__(256, 2) void main_kernel(
    const float* __restrict__ hidden, const int* __restrict__ mask,
    const float* __restrict__ gamma, const float* __restrict__ beta,
    const float* __restrict__ c2g, const float* __restrict__ code_out,
    const unsigned short* __restrict__ Wb, const unsigned short* __restrict__ CBb,
    float* __restrict__ loss_acc, float* __restrict__ out) {

  __shared__ union {
    struct { unsigned short A[64 * 40]; unsigned short Bw[256 * 40]; } p1;  // 25600 B
    unsigned short CB[256 * 40];                                            // 20480 B
  } st;
  __shared__ unsigned short Z[64 * 264];   // z tile, bf16, padded stride (33792 B)
  __shared__ float z2[64];
  __shared__ float c2s[512];
  __shared__ float sminv[4 * 64];
  __shared__ int   sminc[4 * 64];
  __shared__ int   ridx[64];

  const int t    = threadIdx.x;
  const int lane = t & 63;
  const int w    = t >> 6;        // wave id 0..3
  const int l15  = lane & 15;
  const int quad = lane >> 4;
  const int row0 = blockIdx.x * 64;

  // stage c2 into LDS (no ordering hazard; consumed after later barriers)
  c2s[t]       = c2g[t];
  c2s[t + 256] = c2g[t + 256];

  const f32x4 zf = {0.f, 0.f, 0.f, 0.f};

  // ---------------- Phase 1: Z = H * W_in^T ----------------
  f32x4 acc1[4][4];
  #pragma unroll
  for (int i = 0; i < 4; i++)
    #pragma unroll
    for (int j = 0; j < 4; j++) acc1[i][j] = zf;

  const int arow = t >> 2;   // 0..63
  const int akq  = t & 3;    // 0..3
  const float* hsrc = hidden + (size_t)(row0 + arow) * 256 + akq * 8;
  unsigned short* Ast = st.p1.A + arow * 40 + akq * 8;

  for (int ks = 0; ks < 8; ks++) {
    { // stage A tile 64x32 (fp32 -> bf16)
      const float4* p = (const float4*)(hsrc + ks * 32);
      float4 x0 = p[0], x1 = p[1];
      bf16x8 v;
      v[0] = (short)f2bf(x0.x); v[1] = (short)f2bf(x0.y);
      v[2] = (short)f2bf(x0.z); v[3] = (short)f2bf(x0.w);
      v[4] = (short)f2bf(x1.x); v[5] = (short)f2bf(x1.y);
      v[6] = (short)f2bf(x1.z); v[7] = (short)f2bf(x1.w);
      *(bf16x8*)Ast = v;
    }
    #pragma unroll
    for (int it = 0; it < 4; it++) { // stage W_in tile 256x32 (bf16 from ws)
      int idx = t + it * 256;
      int rrow = idx >> 2, kq = idx & 3;
      bf16x8 v = *(const bf16x8*)(Wb + rrow * 256 + ks * 32 + kq * 8);
      *(bf16x8*)(st.p1.Bw + rrow * 40 + kq * 8) = v;
    }
    __syncthreads();
    bf16x8 a[4];
    #pragma unroll
    for (int i = 0; i < 4; i++)
      a[i] = *(const bf16x8*)(st.p1.A + (i * 16 + l15) * 40 + quad * 8);
    #pragma unroll
    for (int j = 0; j < 4; j++) {
      bf16x8 bb = *(const bf16x8*)(st.p1.Bw + (w * 64 + j * 16 + l15) * 40 + quad * 8);
      #pragma unroll
      for (int i = 0; i < 4; i++)
        acc1[i][j] = __builtin_amdgcn_mfma_f32_16x16x32_bf16(a[i], bb, acc1[i][j], 0, 0, 0);
    }
    __syncthreads();
  }

  // epilogue: Z (bf16) to LDS.  C/D layout: row = quad*4+reg, col = lane&15
  #pragma unroll
  for (int i = 0; i < 4; i++)
    #pragma unroll
    for (int j = 0; j < 4; j++)
      #pragma unroll
      for (int r = 0; r < 4; r++) {
        int zr = i * 16 + quad * 4 + r;
        int zc = w * 64 + j * 16 + l15;
        Z[zr * 264 + zc] = f2bf(acc1[i][j][r]);
      }
  __syncthreads();

  { // |z|^2 per row (from bf16 z, consistent with scores)
    int zr = t >> 2, part = t & 3;
    float s = 0.f;
    const unsigned short* zp = Z + zr * 264 + part * 64;
    #pragma unroll
    for (int c = 0; c < 64; c += 8) {
      bf16x8 v = *(const bf16x8*)(zp + c);
      #pragma unroll
      for (int e = 0; e < 8; e++) { float f = bf2f((unsigned short)v[e]); s += f * f; }
    }
    s += __shfl_xor(s, 1);
    s += __shfl_xor(s, 2);
    if (part == 0) z2[zr] = s;
  }
  __syncthreads();

  // ---------------- Phase 2: scores + argmin ----------------
  float runv[16];
  int   runc[16];
  #pragma unroll
  for (int r = 0; r < 16; r++) { runv[r] = 3.4e38f; runc[r] = 0; }

  for (int pass = 0; pass < 2; pass++) {
    f32x4 acc2[4][4];
    #pragma unroll
    for (int i = 0; i < 4; i++)
      #pragma unroll
      for (int j = 0; j < 4; j++) acc2[i][j] = zf;

    for (int ks = 0; ks < 8; ks++) {
      #pragma unroll
      for (int it = 0; it < 4; it++) { // stage 256 codes x 32k
        int idx = t + it * 256;
        int rrow = idx >> 2, kq = idx & 3;
        bf16x8 v = *(const bf16x8*)(CBb + (pass * 256 + rrow) * 256 + ks * 32 + kq * 8);
        *(bf16x8*)(st.CB + rrow * 40 + kq * 8) = v;
      }
      __syncthreads();
      bf16x8 a[4];
      #pragma unroll
      for (int i = 0; i < 4; i++)
        a[i] = *(const bf16x8*)(Z + (i * 16 + l15) * 264 + ks * 32 + quad * 8);
      #pragma unroll
      for (int j = 0; j < 4; j++) {
        bf16x8 bb = *(const bf16x8*)(st.CB + (w * 64 + j * 16 + l15) * 40 + quad * 8);
        #pragma unroll
        for (int i = 0; i < 4; i++)
          acc2[i][j] = __builtin_amdgcn_mfma_f32_16x16x32_bf16(a[i], bb, acc2[i][j], 0, 0, 0);
      }
      __syncthreads();
    }
    // fold scores into running (val, idx)
    #pragma unroll
    for (int i = 0; i < 4; i++)
      #pragma unroll
      for (int j = 0; j < 4; j++) {
        int code = pass * 256 + w * 64 + j * 16 + l15;
        float cc = c2s[code];
        #pragma unroll
        for (int r = 0; r < 4; r++) {
          float s = cc - 2.f * acc2[i][j][r];
          int ri = i * 4 + r;
          if (s < runv[ri]) { runv[ri] = s; runc[ri] = code; }
        }
      }
  }

  // reduce across the 16 lanes of each quad group (same rows, different cols)
  #pragma unroll
  for (int ri = 0; ri < 16; ri++) {
    float v = runv[ri]; int c = runc[ri];
    #pragma unroll
    for (int m = 1; m < 16; m <<= 1) {
      float ov = __shfl_xor(v, m);
      int   oc = __shfl_xor(c, m);
      if (ov < v || (ov == v && oc < c)) { v = ov; c = oc; }
    }
    if (l15 == 0) {
      int i = ri >> 2, r = ri & 3;
      int row = i * 16 + quad * 4 + r;
      sminv[w * 64 + row] = v;
      sminc[w * 64 + row] = c;
    }
  }
  __syncthreads();

  if (t < 64) { // merge 4 waves, finalize idx + dist, block loss sum
    int row = t;
    float bv = sminv[row]; int bc = sminc[row];
    #pragma unroll
    for (int ww = 1; ww < 4; ww++) {
      float v = sminv[ww * 64 + row]; int c = sminc[ww * 64 + row];
      if (v < bv || (v == bv && c < bc)) { bv = v; bc = c; }
    }
    ridx[row] = bc;
    float dist = z2[row] + bv;
    #pragma unroll
    for (int m = 1; m < 64; m <<= 1) dist += __shfl_xor(dist, m);
    if (t == 0) atomicAdd(loss_acc, dist);
  }
  __syncthreads();

  // ---------------- Phase 3: h + mask*code_out[idx], LayerNorm ----------------
  {
    float4 g4 = *(const float4*)(gamma + lane * 4);
    float4 b4 = *(const float4*)(beta + lane * 4);
    for (int rr = 0; rr < 16; rr++) {
      int row = w * 16 + rr;
      int gr  = row0 + row;
      float4 h = *(const float4*)(hidden + (size_t)gr * 256 + lane * 4);
      int code = ridx[row];
      float4 o = *(const float4*)(code_out + code * 256 + lane * 4);
      float mf = mask[gr] ? 1.f : 0.f;
      h.x += mf * o.x; h.y += mf * o.y; h.z += mf * o.z; h.w += mf * o.w;
      float s  = h.x + h.y + h.z + h.w;
      float sq = h.x * h.x + h.y * h.y + h.z * h.z + h.w * h.w;
      #pragma unroll
      for (int m = 1; m < 64; m <<= 1) { s += __shfl_xor(s, m); sq += __shfl_xor(sq, m); }
      float mean = s * (1.f / 256.f);
      float var  = sq * (1.f / 256.f) - mean * mean;
      float rstd = rsqrtf(var + LN_EPS);
      float4 res;
      res.x = (h.x - mean) * rstd * g4.x + b4.x;
      res.y = (h.y - mean) * rstd * g4.y + b4.y;
      res.z = (h.z - mean) * rstd * g4.z + b4.z;
      res.w = (h.w - mean) * rstd * g4.w + b4.w;
      *(float4*)(out + (size_t)gr * 256 + lane * 4) = res;
    }
  }
}

__global__ void loss_kernel(const float* __restrict__ loss_acc, float* __restrict__ out) {
  out[16777216] = 1.25f * loss_acc[0] * (1.f / 16777216.f);
}

extern "C" void kernel_launch(void* const* d_in, const int* in_sizes, int n_in,
                              void* d_out, int out_size, void* d_ws, size_t ws_size,
                              hipStream_t stream) {
  (void)in_sizes; (void)n_in; (void)out_size; (void)ws_size;
  const float* hidden   = (const float*)d_in[0];
  const int*   mask     = (const int*)d_in[1];
  const float* codebook = (const float*)d_in[2];
  const float* W_in     = (const float*)d_in[3];
  const float* W_out    = (const float*)d_in[4];
  const float* gamma    = (const float*)d_in[5];
  const float* beta     = (const float*)d_in[6];
  float* out = (float*)d_out;

  float* wsf      = (float*)d_ws;
  float* loss_acc = wsf;                 // [1]
  float* c2       = wsf + 64;            // [512]
  float* code_out = wsf + 64 + 512;      // [512*256]
  unsigned short* Wb  = (unsigned short*)(wsf + 64 + 512 + 512 * 256);  // [256*256] bf16
  unsigned short* CBb = Wb + 256 * 256;                                  // [512*256] bf16

  prep_kernel<<<1280, 256, 0, stream>>>(codebook, W_in, W_out, loss_acc, c2, code_out, Wb, CBb);
  main_kernel<<<1024, 256, 0, stream>>>(hidden, mask, gamma, beta, c2, code_out, Wb, CBb, loss_acc, out);
  loss_kernel<<<1, 1, 0, stream>>>(loss_acc, out);
}